// Round 1
// baseline (360.645 us; speedup 1.0000x reference)
//
#include <hip/hip_runtime.h>

// out[b,o] = sum_e ( relu(relu(x[b,e,:]@W1[e]+b1[e])@W2[e]+b2[e]) @ W3[e] + b3[e] )
// E=16, DIN=128, H=512, DOUT=64, B=8192.  94.5 GFLOP, AI~1000 -> compute bound, bf16 MFMA.
//
// Plan:
//  - prep kernel: transpose+convert weights fp32[k][n] -> bf16[n][k] in d_ws so that
//    MFMA B-fragments are 16B contiguous per lane, loaded straight from global (L2-resident).
//  - fused kernel: WG(512 thr) = 64 batch rows x 4 experts. X A-frags fp32->bf16 on the fly
//    from global. H1/H2 round-trip through one 64KB swizzled LDS tile. O accumulated in
//    registers across the expert loop; hardware fp32 atomicAdd into zeroed d_out.

#define NE   16
#define NDIN 128
#define NH   512
#define NDO  64
#define NB   8192

using bf16x8 = __attribute__((ext_vector_type(8))) __bf16;
using f32x4  = __attribute__((ext_vector_type(4))) float;

__device__ __forceinline__ unsigned short f2bf(float f) {
    union { float f; unsigned u; } v; v.f = f;
    unsigned r = v.u + 0x7FFFu + ((v.u >> 16) & 1u);   // RNE
    return (unsigned short)(r >> 16);
}

__device__ __forceinline__ bf16x8 cvt8(float4 a, float4 b) {
    union { unsigned short s[8]; bf16x8 v; } r;
    r.s[0] = f2bf(a.x); r.s[1] = f2bf(a.y); r.s[2] = f2bf(a.z); r.s[3] = f2bf(a.w);
    r.s[4] = f2bf(b.x); r.s[5] = f2bf(b.y); r.s[6] = f2bf(b.z); r.s[7] = f2bf(b.w);
    return r.v;
}

__device__ __forceinline__ f32x4 fzero() { f32x4 z = {0.f, 0.f, 0.f, 0.f}; return z; }

// Swizzled index (ushort units) into the 64x512 bf16 LDS tile.
// 16B granules XOR'd by row&15: ds_read_b128 A-frags land 2-way (free),
// epilogue b16 writes worst-case 4-way (1.58x, minor op class).
__device__ __forceinline__ int shidx(int m, int n) {
    return m * NH + ((((n >> 3) ^ (m & 15))) << 3) + (n & 7);
}

// ---------------- prep: fp32 [e][R][C] -> bf16 [e][C][R] ----------------
__global__ __launch_bounds__(256) void transpose_cvt(const float* __restrict__ src,
                                                     unsigned short* __restrict__ dst,
                                                     int R, int C) {
    __shared__ float tile[64][65];
    const int e  = blockIdx.z;
    const int r0 = blockIdx.x * 64, c0 = blockIdx.y * 64;
    const float* s = src + (size_t)e * R * C;
    unsigned short* d = dst + (size_t)e * R * C;
    const int t = threadIdx.x;
#pragma unroll
    for (int i = 0; i < 4; ++i) {
        int f = i * 256 + t;
        int r = f >> 4, c4 = (f & 15) * 4;
        const float4 v = *(const float4*)(s + (size_t)(r0 + r) * C + c0 + c4);
        tile[r][c4 + 0] = v.x; tile[r][c4 + 1] = v.y;
        tile[r][c4 + 2] = v.z; tile[r][c4 + 3] = v.w;
    }
    __syncthreads();
#pragma unroll
    for (int i = 0; i < 4; ++i) {
        int f = i * 256 + t;
        int cc = f >> 4, rb = (f & 15) * 4;
        ushort4 o;
        o.x = f2bf(tile[rb + 0][cc]);
        o.y = f2bf(tile[rb + 1][cc]);
        o.z = f2bf(tile[rb + 2][cc]);
        o.w = f2bf(tile[rb + 3][cc]);
        *(ushort4*)(d + (size_t)(c0 + cc) * R + r0 + rb) = o;
    }
}

// ---------------- fused 3-layer expert MLP ----------------
__global__ __launch_bounds__(512, 2) void moe_fused(
    const float* __restrict__ x,            // [B][E][DIN]
    const float* __restrict__ b1,           // [E][H]
    const float* __restrict__ b2,           // [E][H]
    const float* __restrict__ b3,           // [E][DOUT]
    const unsigned short* __restrict__ W1t, // [E][H][DIN]  bf16
    const unsigned short* __restrict__ W2t, // [E][H][H]    bf16
    const unsigned short* __restrict__ W3t, // [E][DOUT][H] bf16
    float* __restrict__ out)                // [B][DOUT]  (pre-zeroed)
{
    __shared__ unsigned short sH[64 * NH];  // 64KB: holds relu(H1), then relu(H2)

    const int tid  = threadIdx.x;
    const int wave = tid >> 6;
    const int lane = tid & 63;
    const int q    = lane >> 4;   // k-chunk quad
    const int l16  = lane & 15;   // row (A) / col (B) within 16
    const int b0   = blockIdx.x * 64;
    const int eg0  = blockIdx.y * 4;
    const int nb   = wave * 64;   // this wave's n-chunk for layers 1/2

    f32x4 oacc[4];
#pragma unroll
    for (int m = 0; m < 4; ++m) oacc[m] = fzero();

    for (int ei = 0; ei < 4; ++ei) {
        const int e = eg0 + ei;
        __syncthreads();  // previous layer-3 sH reads complete before we overwrite sH

        // ---------------- layer 1: sH = relu(X @ W1 + b1) ----------------
        {
            const unsigned short* Wp = W1t + (size_t)e * NH * NDIN;
            const float* xp[4];
#pragma unroll
            for (int m = 0; m < 4; ++m)
                xp[m] = x + ((size_t)(b0 + m * 16 + l16) * NE + e) * NDIN + q * 8;

            f32x4 acc[4][4];
#pragma unroll
            for (int m = 0; m < 4; ++m)
#pragma unroll
                for (int n = 0; n < 4; ++n) acc[m][n] = fzero();

            bf16x8 afr[2][4], bfr[2][4];
#pragma unroll
            for (int m = 0; m < 4; ++m) {
                float4 u0 = *(const float4*)(xp[m]);
                float4 u1 = *(const float4*)(xp[m] + 4);
                afr[0][m] = cvt8(u0, u1);
            }
#pragma unroll
            for (int n = 0; n < 4; ++n)
                bfr[0][n] = *(const bf16x8*)(Wp + (size_t)(nb + n * 16 + l16) * NDIN + q * 8);

#pragma unroll
            for (int kt = 0; kt < 4; ++kt) {
                const int cur = kt & 1, nxt = cur ^ 1;
                if (kt < 3) {
                    const int k1 = (kt + 1) * 32;
#pragma unroll
                    for (int n = 0; n < 4; ++n)
                        bfr[nxt][n] = *(const bf16x8*)(Wp + (size_t)(nb + n * 16 + l16) * NDIN + k1 + q * 8);
#pragma unroll
                    for (int m = 0; m < 4; ++m) {
                        float4 u0 = *(const float4*)(xp[m] + k1);
                        float4 u1 = *(const float4*)(xp[m] + k1 + 4);
                        afr[nxt][m] = cvt8(u0, u1);
                    }
                }
#pragma unroll
                for (int m = 0; m < 4; ++m)
#pragma unroll
                    for (int n = 0; n < 4; ++n)
                        acc[m][n] = __builtin_amdgcn_mfma_f32_16x16x32_bf16(
                            afr[cur][m], bfr[cur][n], acc[m][n], 0, 0, 0);
            }
            // epilogue: bias + relu -> bf16 -> sH
#pragma unroll
            for (int n = 0; n < 4; ++n) {
                const int col = nb + n * 16 + l16;
                const float bias = b1[e * NH + col];
#pragma unroll
                for (int m = 0; m < 4; ++m)
#pragma unroll
                    for (int r = 0; r < 4; ++r) {
                        float v = acc[m][n][r] + bias;
                        v = fmaxf(v, 0.f);
                        sH[shidx(m * 16 + q * 4 + r, col)] = f2bf(v);
                    }
            }
        }
        __syncthreads();  // H1 visible to all waves

        // ---------------- layer 2: acc2 = H1 @ W2 (regs) ----------------
        f32x4 acc2[4][4];
#pragma unroll
        for (int m = 0; m < 4; ++m)
#pragma unroll
            for (int n = 0; n < 4; ++n) acc2[m][n] = fzero();
        {
            const unsigned short* Wp = W2t + (size_t)e * NH * NH;
            bf16x8 afr[2][4], bfr[2][4];
#pragma unroll
            for (int m = 0; m < 4; ++m)
                afr[0][m] = *(const bf16x8*)&sH[shidx(m * 16 + l16, q * 8)];
#pragma unroll
            for (int n = 0; n < 4; ++n)
                bfr[0][n] = *(const bf16x8*)(Wp + (size_t)(nb + n * 16 + l16) * NH + q * 8);

#pragma unroll
            for (int kt = 0; kt < 16; ++kt) {
                const int cur = kt & 1, nxt = cur ^ 1;
                if (kt < 15) {
                    const int k1 = (kt + 1) * 32 + q * 8;
#pragma unroll
                    for (int n = 0; n < 4; ++n)
                        bfr[nxt][n] = *(const bf16x8*)(Wp + (size_t)(nb + n * 16 + l16) * NH + k1);
#pragma unroll
                    for (int m = 0; m < 4; ++m)
                        afr[nxt][m] = *(const bf16x8*)&sH[shidx(m * 16 + l16, k1)];
                }
#pragma unroll
                for (int m = 0; m < 4; ++m)
#pragma unroll
                    for (int n = 0; n < 4; ++n)
                        acc2[m][n] = __builtin_amdgcn_mfma_f32_16x16x32_bf16(
                            afr[cur][m], bfr[cur][n], acc2[m][n], 0, 0, 0);
            }
        }
        __syncthreads();  // all H1 reads done before overwrite

        // epilogue: bias + relu -> bf16 -> sH (now H2)
#pragma unroll
        for (int n = 0; n < 4; ++n) {
            const int col = nb + n * 16 + l16;
            const float bias = b2[e * NH + col];
#pragma unroll
            for (int m = 0; m < 4; ++m)
#pragma unroll
                for (int r = 0; r < 4; ++r) {
                    float v = acc2[m][n][r] + bias;
                    v = fmaxf(v, 0.f);
                    sH[shidx(m * 16 + q * 4 + r, col)] = f2bf(v);
                }
        }
        __syncthreads();  // H2 visible

        // ---------------- layer 3: waves 0-3, O += H2 @ W3 ----------------
        if (wave < 4) {
            const unsigned short* Wp = W3t + (size_t)e * NDO * NH;
            const int ncol = wave * 16 + l16;
            bf16x8 afr[2][4], bfr2[2];
#pragma unroll
            for (int m = 0; m < 4; ++m)
                afr[0][m] = *(const bf16x8*)&sH[shidx(m * 16 + l16, q * 8)];
            bfr2[0] = *(const bf16x8*)(Wp + (size_t)ncol * NH + q * 8);

#pragma unroll
            for (int kt = 0; kt < 16; ++kt) {
                const int cur = kt & 1, nxt = cur ^ 1;
                if (kt < 15) {
                    const int k1 = (kt + 1) * 32 + q * 8;
                    bfr2[nxt] = *(const bf16x8*)(Wp + (size_t)ncol * NH + k1);
#pragma unroll
                    for (int m = 0; m < 4; ++m)
                        afr[nxt][m] = *(const bf16x8*)&sH[shidx(m * 16 + l16, k1)];
                }
#pragma unroll
                for (int m = 0; m < 4; ++m)
                    oacc[m] = __builtin_amdgcn_mfma_f32_16x16x32_bf16(
                        afr[cur][m], bfr2[cur], oacc[m], 0, 0, 0);
            }
        }
    }

    // ---------------- final: bias-sum + atomic accumulate ----------------
    if (wave < 4) {
        const int col = wave * 16 + l16;
        float bs = 0.f;
#pragma unroll
        for (int ei = 0; ei < 4; ++ei) bs += b3[(eg0 + ei) * NDO + col];
#pragma unroll
        for (int m = 0; m < 4; ++m)
#pragma unroll
            for (int r = 0; r < 4; ++r) {
                const int row = b0 + m * 16 + q * 4 + r;
                unsafeAtomicAdd(out + (size_t)row * NDO + col, oacc[m][r] + bs);
            }
    }
}

extern "C" void kernel_launch(void* const* d_in, const int* in_sizes, int n_in,
                              void* d_out, int out_size, void* d_ws, size_t ws_size,
                              hipStream_t stream) {
    const float* x  = (const float*)d_in[0];
    const float* W1 = (const float*)d_in[1];
    const float* b1 = (const float*)d_in[2];
    const float* W2 = (const float*)d_in[3];
    const float* b2 = (const float*)d_in[4];
    const float* W3 = (const float*)d_in[5];
    const float* b3 = (const float*)d_in[6];
    float* out = (float*)d_out;

    // workspace: bf16 transposed weights, 11.5 MB total
    unsigned short* W1t = (unsigned short*)d_ws;            // [E][H][DIN]
    unsigned short* W2t = W1t + (size_t)NE * NH * NDIN;     // [E][H][H]
    unsigned short* W3t = W2t + (size_t)NE * NH * NH;       // [E][DOUT][H]

    hipMemsetAsync(d_out, 0, (size_t)out_size * sizeof(float), stream);

    transpose_cvt<<<dim3(NDIN / 64, NH / 64, NE), 256, 0, stream>>>(W1, W1t, NDIN, NH);
    transpose_cvt<<<dim3(NH / 64, NH / 64, NE),   256, 0, stream>>>(W2, W2t, NH, NH);
    transpose_cvt<<<dim3(NH / 64, NDO / 64, NE),  256, 0, stream>>>(W3, W3t, NH, NDO);

    moe_fused<<<dim3(NB / 64, NE / 4), 512, 0, stream>>>(x, b1, b2, b3, W1t, W2t, W3t, out);
}